// Round 8
// baseline (323.675 us; speedup 1.0000x reference)
//
#include <hip/hip_runtime.h>

typedef __attribute__((ext_vector_type(4))) float f32x4;
typedef __attribute__((ext_vector_type(8))) __bf16 bf16x8;
typedef __attribute__((ext_vector_type(4))) __bf16 bf16x4;

__device__ __forceinline__ void gload_lds16(const __bf16* g, __bf16* l) {
  __builtin_amdgcn_global_load_lds(
      (const __attribute__((address_space(1))) unsigned int*)(g),
      (__attribute__((address_space(3))) unsigned int*)(l), 16, 0, 0);
}

// ---------------- prep: weight transposes + x convert + pad_or, one launch --------
__global__ __launch_bounds__(256) void prep(
    const float* __restrict__ Wq, const float* __restrict__ Wk,
    const float* __restrict__ Wv, const float* __restrict__ Wo,
    const float4* __restrict__ x, const unsigned long long* __restrict__ pad,
    __bf16* __restrict__ Wqkvt, __bf16* __restrict__ Wot,
    bf16x4* __restrict__ xb, unsigned char* __restrict__ pad64) {
  const int bx = blockIdx.x, by = blockIdx.y;
  const int tx = threadIdx.x, ty = threadIdx.y;
  const int tid = ty * 32 + tx;
  if (bx >= 160) {
    int i = ((bx - 160) * 64 + by) * 256 + tid;
    float4 v = x[i];
    bf16x4 o = {(__bf16)v.x, (__bf16)v.y, (__bf16)v.z, (__bf16)v.w};
    xb[i] = o;
    return;
  }
  if (bx == 0 && by == 0 && tid < 64) {
    unsigned long long acc = 0;
#pragma unroll
    for (int i = 0; i < 8; ++i) acc |= pad[tid * 8 + i];
    pad64[tid] = (acc != 0) ? 1 : 0;
  }
  __shared__ float t[32][33];
  const float* src; __bf16* dst; int ss, c0;
  if (bx < 64)      { src = Wq; dst = Wqkvt;                       ss = 2048; c0 = bx * 32; }
  else if (bx < 80) { src = Wk; dst = Wqkvt + (size_t)2048 * 2048; ss = 512;  c0 = (bx - 64) * 32; }
  else if (bx < 96) { src = Wv; dst = Wqkvt + (size_t)2560 * 2048; ss = 512;  c0 = (bx - 80) * 32; }
  else              { src = Wo; dst = Wot;                         ss = 2048; c0 = (bx - 96) * 32; }
  const int r0 = by * 32;
#pragma unroll
  for (int i = ty; i < 32; i += 8)
    t[i][tx] = src[(size_t)(r0 + i) * ss + c0 + tx];
  __syncthreads();
#pragma unroll
  for (int i = ty; i < 32; i += 8)
    dst[(size_t)(c0 + i) * 2048 + r0 + tx] = (__bf16)t[tx][i];
}

// ---------------- QKV GEMM: 128x192 tile, BK=64, safe 2-phase double-buffer -------
__device__ __forceinline__ void stage5(const __bf16* aS, const __bf16* bS,
                                       __bf16* Ab, __bf16* Bb, int wb8, size_t kt) {
#pragma unroll
  for (int l = 0; l < 2; ++l)
    gload_lds16(aS + (size_t)l * 131072 + kt, Ab + l * 4096 + wb8);
#pragma unroll
  for (int l = 0; l < 3; ++l)
    gload_lds16(bS + (size_t)l * 131072 + kt, Bb + l * 4096 + wb8);
}

__global__ __launch_bounds__(512, 4) void gemm_qkv192(
    const __bf16* __restrict__ A, const __bf16* __restrict__ Bt,
    __bf16* __restrict__ Qb, __bf16* __restrict__ Kb, __bf16* __restrict__ Vt) {
  extern __shared__ __bf16 smem[];
  const int K = 2048;
  const int tid = threadIdx.x;
  const int lane = tid & 63, w = tid >> 6;
  const int c15 = lane & 15, quad = lane >> 4;
  const int wm = w >> 2, wn = w & 3;
  const int id = blockIdx.x;
  const int swz = (id & 7) * 64 + (id >> 3);   // bijective: 512 = 8*64
  const int m0 = (swz >> 4) * 128, n0 = (swz & 15) * 192;

  const int srow = tid >> 3;
  const int scol = ((tid & 7) ^ (srow & 7)) * 8;
  const __bf16* aSrc = A + (size_t)(m0 + srow) * K + scol;
  const __bf16* bSrc = Bt + (size_t)(n0 + srow) * K + scol;
  const int wb8 = (tid & 448) * 8;   // wave-uniform LDS base (elems)
  // buffers (elems): A0 @0 (8192), B0 @8192 (12288), A1 @20480, B1 @28672
  f32x4 acc[4][3] = {};

  stage5(aSrc, bSrc, smem, smem + 8192, wb8, 0);
  __syncthreads();

  for (int t = 0; t < 32; ++t) {
    __bf16* Ab = smem + (t & 1) * 20480;
    __bf16* Bb = Ab + 8192;
    if (t < 31) {
      __bf16* An = smem + ((t + 1) & 1) * 20480;
      stage5(aSrc, bSrc, An, An + 8192, wb8, (size_t)(t + 1) * 64);
    }
    bf16x8 bF[3][2];
#pragma unroll
    for (int j = 0; j < 3; ++j) {
      int RB = wn * 48 + j * 16 + c15;
#pragma unroll
      for (int h = 0; h < 2; ++h)
        bF[j][h] = *(const bf16x8*)(Bb + RB * 64 + (((h * 4 + quad) ^ (RB & 7)) * 8));
    }
    __builtin_amdgcn_s_setprio(1);
#pragma unroll
    for (int i = 0; i < 4; ++i) {
      int RA = wm * 64 + i * 16 + c15;
      bf16x8 a0 = *(const bf16x8*)(Ab + RA * 64 + ((quad ^ (RA & 7)) * 8));
      bf16x8 a1 = *(const bf16x8*)(Ab + RA * 64 + (((4 + quad) ^ (RA & 7)) * 8));
#pragma unroll
      for (int j = 0; j < 3; ++j) {
        acc[i][j] = __builtin_amdgcn_mfma_f32_16x16x32_bf16(a0, bF[j][0], acc[i][j], 0, 0, 0);
        acc[i][j] = __builtin_amdgcn_mfma_f32_16x16x32_bf16(a1, bF[j][1], acc[i][j], 0, 0, 0);
      }
    }
    __builtin_amdgcn_s_setprio(0);
    __syncthreads();
  }

  // ---- epilogue: per-wave 10KB LDS chunk; waves independent (no cross-wave sync).
  const int b = m0 >> 11;
  const int s0 = m0 & 2047;
  const int colbase = n0 + wn * 48;
  __bf16* st = smem + w * 5120;

#pragma unroll
  for (int i = 0; i < 4; ++i)
#pragma unroll
    for (int j = 0; j < 3; ++j)
#pragma unroll
      for (int r = 0; r < 4; ++r)
        st[(i * 16 + quad * 4 + r) * 56 + j * 16 + c15] = (__bf16)acc[i][j][r];
  __syncthreads();

  // Q/K granules: coalesced 16B row chunks
  {
    const int g = lane & 7, sl = lane >> 3;
    int c = colbase + g * 8;
    if (g < 6 && c < 2560) {
      __bf16* hp = (c < 2048)
          ? Qb + (((size_t)b * 16 + (c >> 7)) * 2048 + s0 + wm * 64) * 128 + (c & 127)
          : Kb + (((size_t)b * 4 + ((c - 2048) >> 7)) * 2048 + s0 + wm * 64) * 128 + (c & 127);
#pragma unroll
      for (int it = 0; it < 8; ++it) {
        int s = it * 8 + sl;
        *(bf16x8*)(hp + (size_t)s * 128) = *(const bf16x8*)(st + s * 56 + g * 8);
      }
    }
  }
  // V granules: transpose via column gather, 16B contiguous-in-s writes
#pragma unroll
  for (int it = 0; it < 6; ++it) {
    int lc = it * 8 + (lane >> 3);
    int c = colbase + lc;
    if (c >= 2560) {
      int sc = lane & 7;
      bf16x8 o;
#pragma unroll
      for (int rr = 0; rr < 8; ++rr) o[rr] = st[(sc * 8 + rr) * 56 + lc];
      __bf16* vp = Vt + (((size_t)b * 4 + ((c - 2560) >> 7)) * 128 + ((c - 2560) & 127)) * 2048
                   + s0 + wm * 64 + sc * 8;
      *(bf16x8*)vp = o;
    }
  }
}

// ---------------- RMSNorm + RoPE, in-place on bf16 Q/K ----------------
__global__ __launch_bounds__(256) void norm_rope(
    __bf16* __restrict__ Qb, __bf16* __restrict__ Kb,
    const float* __restrict__ qw, const float* __restrict__ kw,
    const float* __restrict__ cosT, const float* __restrict__ sinT) {
  const int tid = threadIdx.x, w = tid >> 6, lane = tid & 63;
  const int v = blockIdx.x * 4 + w;
  const bool isQ = v < 65536;
  __bf16* base = isQ ? Qb + (size_t)v * 128 : Kb + (size_t)(v - 65536) * 128;
  const int s = v & 2047;
  float x1 = (float)base[lane], x2 = (float)base[lane + 64];
  float ss = x1 * x1 + x2 * x2;
#pragma unroll
  for (int d = 32; d; d >>= 1) ss += __shfl_xor(ss, d);
  float rn = rsqrtf(ss * (1.0f / 128.0f) + 1e-8f);
  const float* wt = isQ ? qw : kw;
  float n1 = x1 * rn * (1.0f + wt[lane]);
  float n2 = x2 * rn * (1.0f + wt[lane + 64]);
  float c1 = cosT[s * 128 + lane], c2 = cosT[s * 128 + 64 + lane];
  float s1 = sinT[s * 128 + lane], s2 = sinT[s * 128 + 64 + lane];
  const float QSC = 0.08838834764831845f * 1.4426950408889634f;  // scale * log2(e)
  float post = isQ ? QSC : 1.0f;
  base[lane]      = (__bf16)((n1 * c1 - n2 * s1) * post);
  base[lane + 64] = (__bf16)((n2 * c2 + n1 * s2) * post);
}

// ---------------- output projection: 128x128 tile, BK=64, safe 2-phase dbuf -------
__device__ __forceinline__ void stage4(const __bf16* aS, const __bf16* bS,
                                       __bf16* Ab, __bf16* Bb, int wb8, size_t kt) {
#pragma unroll
  for (int l = 0; l < 2; ++l)
    gload_lds16(aS + (size_t)l * 131072 + kt, Ab + l * 4096 + wb8);
#pragma unroll
  for (int l = 0; l < 2; ++l)
    gload_lds16(bS + (size_t)l * 131072 + kt, Bb + l * 4096 + wb8);
}

__global__ __launch_bounds__(512, 4) void gemm_bt128(
    const __bf16* __restrict__ A, const __bf16* __restrict__ Bt,
    float* __restrict__ C) {
  extern __shared__ __bf16 smem[];
  const int K = 2048, N = 2048;
  const int tid = threadIdx.x;
  const int lane = tid & 63, w = tid >> 6;
  const int c15 = lane & 15, quad = lane >> 4;
  const int wm = w >> 2, wn = w & 3;
  const int id = blockIdx.x;
  const int swz = (id & 7) * 64 + (id >> 3);   // bijective: 512 = 8*64
  const int m0 = (swz >> 4) * 128, n0 = (swz & 15) * 128;

  const int srow = tid >> 3;
  const int scol = ((tid & 7) ^ (srow & 7)) * 8;
  const __bf16* aSrc = A + (size_t)(m0 + srow) * K + scol;
  const __bf16* bSrc = Bt + (size_t)(n0 + srow) * K + scol;
  const int wb8 = (tid & 448) * 8;

  f32x4 acc[4][2] = {};

  stage4(aSrc, bSrc, smem, smem + 8192, wb8, 0);
  __syncthreads();

  for (int t = 0; t < 32; ++t) {
    __bf16* Ab = smem + (t & 1) * 16384;
    __bf16* Bb = Ab + 8192;
    if (t < 31) {
      __bf16* An = smem + ((t + 1) & 1) * 16384;
      stage4(aSrc, bSrc, An, An + 8192, wb8, (size_t)(t + 1) * 64);
    }
    bf16x8 bF[2][2];
#pragma unroll
    for (int j = 0; j < 2; ++j) {
      int RB = wn * 32 + j * 16 + c15;
#pragma unroll
      for (int h = 0; h < 2; ++h)
        bF[j][h] = *(const bf16x8*)(Bb + RB * 64 + (((h * 4 + quad) ^ (RB & 7)) * 8));
    }
    __builtin_amdgcn_s_setprio(1);
#pragma unroll
    for (int i = 0; i < 4; ++i) {
      int RA = wm * 64 + i * 16 + c15;
      bf16x8 a0 = *(const bf16x8*)(Ab + RA * 64 + ((quad ^ (RA & 7)) * 8));
      bf16x8 a1 = *(const bf16x8*)(Ab + RA * 64 + (((4 + quad) ^ (RA & 7)) * 8));
#pragma unroll
      for (int j = 0; j < 2; ++j) {
        acc[i][j] = __builtin_amdgcn_mfma_f32_16x16x32_bf16(a0, bF[j][0], acc[i][j], 0, 0, 0);
        acc[i][j] = __builtin_amdgcn_mfma_f32_16x16x32_bf16(a1, bF[j][1], acc[i][j], 0, 0, 0);
      }
    }
    __builtin_amdgcn_s_setprio(0);
    __syncthreads();
  }

#pragma unroll
  for (int i = 0; i < 4; ++i) {
    int r0 = m0 + wm * 64 + i * 16 + quad * 4;
#pragma unroll
    for (int j = 0; j < 2; ++j) {
      int cc = n0 + wn * 32 + j * 16 + c15;
#pragma unroll
      for (int r = 0; r < 4; ++r)
        C[(size_t)(r0 + r) * N + cc] = acc[i][j][r];
    }
  }
}

// ---------------- Flash attention v7: single barrier/iter, K+V dbuf --------------
// Per KV tile t (ONE __syncthreads):
//   sync  [drains stage(t) issued at t-1; all reads of buf[t&1] from t-1 done]
//   stage K(t+1),V(t+1) -> buf[(t+1)&1]   (async; drained by next iter's sync)
//   QK^T (swapped) from Ks[t&1]
//   phase x2: softmax k-half -> P (wave-private, 32x36) -> lgkmcnt(0) ->
//             pf read -> 16 MFMA PV from Vs[t&1]
// P is wave-private: no barrier needed between write and read (in-wave lgkmcnt).
// FP accumulation order identical to v6 (k 0..31 then 32..63 per acc[nb]).
// LDS 73 KiB dyn (Ks x2 32K + Vs x2 32K + Ps 4x32x36 9K) -> 2 blocks/CU.
// Heavy+light pairing: b=0 tiles heavy-first, b=1 light-first, so CU pair
// (c, c+256) sums f(63-x)+f(x) <= 33 iters instead of 36 (identical-work pairing).
__global__ __launch_bounds__(256) void attn(
    const __bf16* __restrict__ Qb, const __bf16* __restrict__ Kb,
    const __bf16* __restrict__ Vt, const unsigned char* __restrict__ pad,
    const unsigned char* __restrict__ pad64, const int* __restrict__ winp,
    __bf16* __restrict__ O) {
  const int S = 2048;
  extern __shared__ __bf16 smem[];
  // Ks[2] @0,@8192 ; Vs[2] @16384,@24576 ; Ps @32768 (1152 elems/wave)
  const int tid = threadIdx.x, w = tid >> 6, lane = tid & 63;
  const int c15 = lane & 15, quad = lane >> 4;
  const int b = blockIdx.z;
  const int q0 = (b == 0) ? ((int)gridDim.x - 1 - (int)blockIdx.x) * 32
                          : (int)blockIdx.x * 32;
  const int kv = blockIdx.y;
  const int h = kv * 4 + w;
  const int W = *winp;
  const unsigned char* padb = pad + (size_t)b * S;
  const unsigned char* pad64b = pad64 + b * 32;
  const __bf16* Qh = Qb + (((size_t)b * 16 + h) * S) * 128;
  const __bf16* Kh = Kb + (((size_t)b * 4 + kv) * S) * 128;
  const __bf16* Vh = Vt + (((size_t)b * 4 + kv) * 128) * (size_t)S;
  __bf16* Pw = smem + 32768 + w * 1152;

  bf16x8 qf0[4], qf1[4];
#pragma unroll
  for (int c = 0; c < 4; ++c) {
    qf0[c] = *(const bf16x8*)(Qh + (size_t)(q0 + c15) * 128 + c * 32 + quad * 8);
    qf1[c] = *(const bf16x8*)(Qh + (size_t)(q0 + 16 + c15) * 128 + c * 32 + quad * 8);
  }

  f32x4 acc0[8] = {}, acc1[8] = {};
  float lsum0 = 0.f, lsum1 = 0.f;
  const int qi0 = q0 + c15, qi1 = q0 + 16 + c15;

  const int krow_i = lane >> 4, kch = lane & 15;
  const int vrow_i = lane >> 3, vch = lane & 7;

  int kb0 = q0 - W; if (kb0 < 0) kb0 = 0; kb0 &= ~63;
  const int kbend = q0 + 31;

  // prologue: stage K(kb0),V(kb0) into buf 0
#pragma unroll
  for (int i = 0; i < 4; ++i) {
    int row = w * 16 + i * 4 + krow_i;
    gload_lds16(Kh + (size_t)(kb0 + row) * 128 + ((kch ^ (row & 15)) * 8),
                smem + (w * 16 + i * 4) * 128);
  }
#pragma unroll
  for (int i = 0; i < 4; ++i) {
    int row = w * 32 + i * 8 + vrow_i;
    gload_lds16(Vh + (size_t)row * S + kb0 + ((vch ^ (row & 7)) * 8),
                smem + 16384 + (w * 32 + i * 8) * 64);
  }

  int ti = 0;
  for (int kb = kb0; kb <= kbend; kb += 64, ++ti) {
    const int cur = ti & 1;
    __bf16* Ksb = smem + cur * 8192;
    __bf16* Vsb = smem + 16384 + cur * 8192;
    __syncthreads();  // drains stage(t) [issued at t-1]; buf[cur^1] readers done

    if (kb + 64 <= kbend) {
      __bf16* Ksn = smem + (cur ^ 1) * 8192;
      __bf16* Vsn = smem + 16384 + (cur ^ 1) * 8192;
#pragma unroll
      for (int i = 0; i < 4; ++i) {
        int row = w * 16 + i * 4 + krow_i;
        gload_lds16(Kh + (size_t)(kb + 64 + row) * 128 + ((kch ^ (row & 15)) * 8),
                    Ksn + (w * 16 + i * 4) * 128);
      }
#pragma unroll
      for (int i = 0; i < 4; ++i) {
        int row = w * 32 + i * 8 + vrow_i;
        gload_lds16(Vh + (size_t)row * S + kb + 64 + ((vch ^ (row & 7)) * 8),
                    Vsn + (w * 32 + i * 8) * 64);
      }
    }

    // swapped QK^T: sf[nb][r] = S[k = kb+nb*16+quad*4+r][q = q0(+16)+c15]
    f32x4 sf0[4], sf1[4];
#pragma unroll
    for (int nb = 0; nb < 4; ++nb) {
      f32x4 ca = {}, cb = {};
#pragma unroll
      for (int c = 0; c < 4; ++c) {
        bf16x8 kf = *(const bf16x8*)(Ksb + (nb * 16 + c15) * 128 + (((c * 4 + quad) ^ c15) * 8));
        ca = __builtin_amdgcn_mfma_f32_16x16x32_bf16(kf, qf0[c], ca, 0, 0, 0);
        cb = __builtin_amdgcn_mfma_f32_16x16x32_bf16(kf, qf1[c], cb, 0, 0, 0);
      }
      sf0[nb] = ca; sf1[nb] = cb;
    }

    const bool fast = (kb + 63 <= q0) && (q0 + 31 - kb <= W) && (pad64b[kb >> 6] == 0);
#pragma unroll
    for (int ph = 0; ph < 2; ++ph) {
      if (fast) {
#pragma unroll
        for (int nb2 = 0; nb2 < 2; ++nb2) {
          const int nb = ph * 2 + nb2;
          float a0 = exp2f(sf0[nb][0]), a1 = exp2f(sf0[nb][1]);
          float a2 = exp2f(sf0[nb][2]), a3 = exp2f(sf0[nb][3]);
          lsum0 += (a0 + a1) + (a2 + a3);
          unsigned int w0, w1;
          asm("v_cvt_pk_bf16_f32 %0, %1, %2" : "=v"(w0) : "v"(a0), "v"(a1));
          asm("v_cvt_pk_bf16_f32 %0, %1, %2" : "=v"(w1) : "v"(a2), "v"(a3));
          unsigned long long pk0 = (unsigned long long)w0 | ((unsigned long long)w1 << 32);
          *(unsigned long long*)(Pw + (size_t)c15 * 36 + nb2 * 16 + quad * 4) = pk0;
          float b0 = exp2f(sf1[nb][0]), b1 = exp2f(sf1[nb][1]);
          float b2 = exp2f(sf1[nb][2]), b3 = exp2f(sf1[nb][3]);
          lsum1 += (b0 + b1) + (b2 + b3);
          unsigned int w2, w3;
          asm("v_cvt_pk_bf16_f32 %0, %1, %2" : "=v"(w2) : "v"(b0), "v"(b1));
          asm("v_cvt_pk_bf16_f32 %0, %1, %2" : "=v"(w3) : "v"(b2), "v"(b3));
          unsigned long long pk1 = (unsigned long long)w2 | ((unsigned long long)w3 << 32);
          *(unsigned long long*)(Pw + (size_t)(16 + c15) * 36 + nb2 * 16 + quad * 4) = pk1;
        }
      } else {
#pragma unroll
        for (int nb2 = 0; nb2 < 2; ++nb2) {
          const int nb = ph * 2 + nb2;
          float p0[4], p1[4];
#pragma unroll
          for (int r = 0; r < 4; ++r) {
            int ki = kb + nb * 16 + quad * 4 + r;
            bool okp = (padb[ki] == 0);
            bool ok0 = (ki <= qi0) && ((qi0 - ki) <= W) && okp;
            bool ok1 = (ki <= qi1) && ((qi1 - ki) <= W) && okp;
            float e0 = exp2f(sf0[nb][r]);
            float e1 = exp2f(sf1[nb][r]);
            p0[r] = ok0 ? e0 : 0.0f;
            p1[r] = ok1 ? e1 : 0.0f;
          }
          lsum0 += (p0[0] + p0[1]) + (p0[2] + p0[3]);
          lsum1 += (p1[0] + p1[1]) + (p1[2] + p1[3]);
          unsigned int w0, w1, w2, w3;
          asm("v_cvt_pk_bf16_f32 %0, %1, %2" : "=v"(w0) : "v"(p0[0]), "v"(p0[1]));
          asm("v_cvt_pk_bf16_f32 %0, %1, %2" : "=v"(w1) : "v"(p0[2]), "v"(p0[3]));
          unsigned long long pk0 = (unsigned long long)w0 | ((unsigned long long)w1 << 32);
          *(unsigned long long*)(Pw + (size_t)c15 * 36 + nb2 * 16 + quad * 4) = pk0;
          asm("v_cvt_pk_bf16_f32 %0, %1, %2" : "=v"(w2) : "v"(p1[0]), "v"(p1[1]));
          asm("v_cvt_pk_bf16_f32 %0, %1, %2" : "=v"(w3) : "v"(p1[2]), "v"(p1[3]));
          unsigned long long pk1 = (unsigned long long)w2 | ((unsigned long long)w3 << 32);
          *(unsigned long long*)(Pw + (size_t)(16 + c15) * 36 + nb2 * 16 + quad * 4) = pk1;
        }
      }
      asm volatile("s_waitcnt lgkmcnt(0)" ::: "memory");
      __builtin_amdgcn_sched_barrier(0);
      bf16x8 pf0 = *(const bf16x8*)(Pw + (size_t)c15 * 36 + quad * 8);
      bf16x8 pf1 = *(const bf16x8*)(Pw + (size_t)(16 + c15) * 36 + quad * 8);
#pragma unroll
      for (int nb = 0; nb < 8; ++nb) {
        int row = nb * 16 + c15;
        bf16x8 vf = *(const bf16x8*)(Vsb + row * 64 + (((ph * 4 + quad) ^ (c15 & 7)) * 8));
        acc0[nb] = __builtin_amdgcn_mfma_f32_16x16x32_bf16(pf0, vf, acc0[nb], 0, 0, 0);
        acc1[nb] = __builtin_amdgcn_mfma_f32_16x16x32_bf16(pf1, vf, acc1[nb], 0, 0, 0);
      }
    }
  }

  // lsum lives at q=c15 (quads hold k-partials); reduce across quads, then
  // redistribute inv to writer lanes (r-th output row of quad block).
  lsum0 += __shfl_xor(lsum0, 16);
  lsum0 += __shfl_xor(lsum0, 32);
  lsum1 += __shfl_xor(lsum1, 16);
  lsum1 += __shfl_xor(lsum1, 32);
  float inv0 = 1.0f / lsum0, inv1 = 1.0f / lsum1;
  float iv0[4], iv1[4];
#pragma unroll
  for (int r = 0; r < 4; ++r) {
    iv0[r] = __shfl(inv0, quad * 4 + r);
    iv1[r] = __shfl(inv1, quad * 4 + r);
  }
#pragma unroll
  for (int nb = 0; nb < 8; ++nb)
#pragma unroll
    for (int r = 0; r < 4; ++r) {
      size_t idx = ((size_t)b * S + q0 + quad * 4 + r) * 2048 + h * 128 + nb * 16 + c15;
      O[idx] = (__bf16)(acc0[nb][r] * iv0[r]);
      O[idx + (size_t)16 * 2048] = (__bf16)(acc1[nb][r] * iv1[r]);
    }
}

// ---------------- launch ----------------
extern "C" void kernel_launch(void* const* d_in, const int* in_sizes, int n_in,
                              void* d_out, int out_size, void* d_ws, size_t ws_size,
                              hipStream_t stream) {
  const float* x    = (const float*)d_in[0];
  const float* Wq   = (const float*)d_in[1];
  const float* Wk   = (const float*)d_in[2];
  const float* Wv   = (const float*)d_in[3];
  const float* Wo   = (const float*)d_in[4];
  const float* qw   = (const float*)d_in[5];
  const float* kw   = (const float*)d_in[6];
  const float* cosT = (const float*)d_in[7];
  const float* sinT = (const float*)d_in[8];
  const unsigned char* pad = (const unsigned char*)d_in[9];
  const int* win    = (const int*)d_in[10];

  char* ws = (char*)d_ws;
  __bf16* xb    = (__bf16*)(ws + 0);          // 4096x2048 bf16        (16 MB)
  __bf16* Wqkvt = (__bf16*)(ws + 16777216);   // 3072x2048 bf16        (12 MB)
  __bf16* Wot   = (__bf16*)(ws + 29360128);   // 2048x2048 bf16        (8 MB)
  __bf16* Qb    = (__bf16*)(ws + 37748736);   // [2][16][2048][128]    (16 MB)
  __bf16* Kb    = (__bf16*)(ws + 54525952);   // [2][4][2048][128]     (4 MB)
  __bf16* Vt    = (__bf16*)(ws + 58720256);   // [2][4][128][2048]     (4 MB)
  __bf16* Ob    = (__bf16*)(ws + 62914560);   // 4096x2048 bf16        (16 MB)
  unsigned char* pad64 = (unsigned char*)(ws + 79691776);  // [2][32]

  static int qkv_attr = (int)hipFuncSetAttribute(
      (const void*)gemm_qkv192, hipFuncAttributeMaxDynamicSharedMemorySize, 81920);
  (void)qkv_attr;
  static int bt_attr = (int)hipFuncSetAttribute(
      (const void*)gemm_bt128, hipFuncAttributeMaxDynamicSharedMemorySize, 65536);
  (void)bt_attr;
  static int at_attr = (int)hipFuncSetAttribute(
      (const void*)attn, hipFuncAttributeMaxDynamicSharedMemorySize, 75264);
  (void)at_attr;

  prep<<<dim3(288, 64, 1), dim3(32, 8, 1), 0, stream>>>(
      Wq, Wk, Wv, Wo, (const float4*)x, (const unsigned long long*)pad,
      Wqkvt, Wot, (bf16x4*)xb, pad64);

  gemm_qkv192<<<dim3(512, 1, 1), 512, 81920, stream>>>(xb, Wqkvt, Qb, Kb, Vt);

  norm_rope<<<20480, 256, 0, stream>>>(Qb, Kb, qw, kw, cosT, sinT);

  attn<<<dim3(64, 4, 2), 256, 75264, stream>>>(Qb, Kb, Vt, pad, pad64, win, Ob);

  gemm_bt128<<<dim3(512, 1, 1), 512, 65536, stream>>>(Ob, Wot, (float*)d_out);
}

// Round 9
// 287.974 us; speedup vs baseline: 1.1240x; 1.1240x over previous
//
#include <hip/hip_runtime.h>

typedef __attribute__((ext_vector_type(4))) float f32x4;
typedef __attribute__((ext_vector_type(8))) __bf16 bf16x8;
typedef __attribute__((ext_vector_type(4))) __bf16 bf16x4;

__device__ __forceinline__ void gload_lds16(const __bf16* g, __bf16* l) {
  __builtin_amdgcn_global_load_lds(
      (const __attribute__((address_space(1))) unsigned int*)(g),
      (__attribute__((address_space(3))) unsigned int*)(l), 16, 0, 0);
}

// ---------------- prep: weight transposes + x convert + pad_or, one launch --------
__global__ __launch_bounds__(256) void prep(
    const float* __restrict__ Wq, const float* __restrict__ Wk,
    const float* __restrict__ Wv, const float* __restrict__ Wo,
    const float4* __restrict__ x, const unsigned long long* __restrict__ pad,
    __bf16* __restrict__ Wqkvt, __bf16* __restrict__ Wot,
    bf16x4* __restrict__ xb, unsigned char* __restrict__ pad64) {
  const int bx = blockIdx.x, by = blockIdx.y;
  const int tx = threadIdx.x, ty = threadIdx.y;
  const int tid = ty * 32 + tx;
  if (bx >= 160) {
    int i = ((bx - 160) * 64 + by) * 256 + tid;
    float4 v = x[i];
    bf16x4 o = {(__bf16)v.x, (__bf16)v.y, (__bf16)v.z, (__bf16)v.w};
    xb[i] = o;
    return;
  }
  if (bx == 0 && by == 0 && tid < 64) {
    unsigned long long acc = 0;
#pragma unroll
    for (int i = 0; i < 8; ++i) acc |= pad[tid * 8 + i];
    pad64[tid] = (acc != 0) ? 1 : 0;
  }
  __shared__ float t[32][33];
  const float* src; __bf16* dst; int ss, c0;
  if (bx < 64)      { src = Wq; dst = Wqkvt;                       ss = 2048; c0 = bx * 32; }
  else if (bx < 80) { src = Wk; dst = Wqkvt + (size_t)2048 * 2048; ss = 512;  c0 = (bx - 64) * 32; }
  else if (bx < 96) { src = Wv; dst = Wqkvt + (size_t)2560 * 2048; ss = 512;  c0 = (bx - 80) * 32; }
  else              { src = Wo; dst = Wot;                         ss = 2048; c0 = (bx - 96) * 32; }
  const int r0 = by * 32;
#pragma unroll
  for (int i = ty; i < 32; i += 8)
    t[i][tx] = src[(size_t)(r0 + i) * ss + c0 + tx];
  __syncthreads();
#pragma unroll
  for (int i = ty; i < 32; i += 8)
    dst[(size_t)(c0 + i) * 2048 + r0 + tx] = (__bf16)t[tx][i];
}

// ---------------- QKV GEMM: 128x192 tile, BK=64, safe 2-phase double-buffer -------
__device__ __forceinline__ void stage5(const __bf16* aS, const __bf16* bS,
                                       __bf16* Ab, __bf16* Bb, int wb8, size_t kt) {
#pragma unroll
  for (int l = 0; l < 2; ++l)
    gload_lds16(aS + (size_t)l * 131072 + kt, Ab + l * 4096 + wb8);
#pragma unroll
  for (int l = 0; l < 3; ++l)
    gload_lds16(bS + (size_t)l * 131072 + kt, Bb + l * 4096 + wb8);
}

__global__ __launch_bounds__(512, 4) void gemm_qkv192(
    const __bf16* __restrict__ A, const __bf16* __restrict__ Bt,
    __bf16* __restrict__ Qb, __bf16* __restrict__ Kb, __bf16* __restrict__ Vt) {
  extern __shared__ __bf16 smem[];
  const int K = 2048;
  const int tid = threadIdx.x;
  const int lane = tid & 63, w = tid >> 6;
  const int c15 = lane & 15, quad = lane >> 4;
  const int wm = w >> 2, wn = w & 3;
  const int id = blockIdx.x;
  const int swz = (id & 7) * 64 + (id >> 3);   // bijective: 512 = 8*64
  const int m0 = (swz >> 4) * 128, n0 = (swz & 15) * 192;

  const int srow = tid >> 3;
  const int scol = ((tid & 7) ^ (srow & 7)) * 8;
  const __bf16* aSrc = A + (size_t)(m0 + srow) * K + scol;
  const __bf16* bSrc = Bt + (size_t)(n0 + srow) * K + scol;
  const int wb8 = (tid & 448) * 8;   // wave-uniform LDS base (elems)
  f32x4 acc[4][3] = {};

  stage5(aSrc, bSrc, smem, smem + 8192, wb8, 0);
  __syncthreads();

  for (int t = 0; t < 32; ++t) {
    __bf16* Ab = smem + (t & 1) * 20480;
    __bf16* Bb = Ab + 8192;
    if (t < 31) {
      __bf16* An = smem + ((t + 1) & 1) * 20480;
      stage5(aSrc, bSrc, An, An + 8192, wb8, (size_t)(t + 1) * 64);
    }
    bf16x8 bF[3][2];
#pragma unroll
    for (int j = 0; j < 3; ++j) {
      int RB = wn * 48 + j * 16 + c15;
#pragma unroll
      for (int h = 0; h < 2; ++h)
        bF[j][h] = *(const bf16x8*)(Bb + RB * 64 + (((h * 4 + quad) ^ (RB & 7)) * 8));
    }
    __builtin_amdgcn_s_setprio(1);
#pragma unroll
    for (int i = 0; i < 4; ++i) {
      int RA = wm * 64 + i * 16 + c15;
      bf16x8 a0 = *(const bf16x8*)(Ab + RA * 64 + ((quad ^ (RA & 7)) * 8));
      bf16x8 a1 = *(const bf16x8*)(Ab + RA * 64 + (((4 + quad) ^ (RA & 7)) * 8));
#pragma unroll
      for (int j = 0; j < 3; ++j) {
        acc[i][j] = __builtin_amdgcn_mfma_f32_16x16x32_bf16(a0, bF[j][0], acc[i][j], 0, 0, 0);
        acc[i][j] = __builtin_amdgcn_mfma_f32_16x16x32_bf16(a1, bF[j][1], acc[i][j], 0, 0, 0);
      }
    }
    __builtin_amdgcn_s_setprio(0);
    __syncthreads();
  }

  // ---- epilogue: per-wave 10KB LDS chunk; waves independent (no cross-wave sync).
  const int b = m0 >> 11;
  const int s0 = m0 & 2047;
  const int colbase = n0 + wn * 48;
  __bf16* st = smem + w * 5120;

#pragma unroll
  for (int i = 0; i < 4; ++i)
#pragma unroll
    for (int j = 0; j < 3; ++j)
#pragma unroll
      for (int r = 0; r < 4; ++r)
        st[(i * 16 + quad * 4 + r) * 56 + j * 16 + c15] = (__bf16)acc[i][j][r];
  __syncthreads();

  // Q/K granules: coalesced 16B row chunks
  {
    const int g = lane & 7, sl = lane >> 3;
    int c = colbase + g * 8;
    if (g < 6 && c < 2560) {
      __bf16* hp = (c < 2048)
          ? Qb + (((size_t)b * 16 + (c >> 7)) * 2048 + s0 + wm * 64) * 128 + (c & 127)
          : Kb + (((size_t)b * 4 + ((c - 2048) >> 7)) * 2048 + s0 + wm * 64) * 128 + (c & 127);
#pragma unroll
      for (int it = 0; it < 8; ++it) {
        int s = it * 8 + sl;
        *(bf16x8*)(hp + (size_t)s * 128) = *(const bf16x8*)(st + s * 56 + g * 8);
      }
    }
  }
  // V granules: transpose via column gather, 16B contiguous-in-s writes
#pragma unroll
  for (int it = 0; it < 6; ++it) {
    int lc = it * 8 + (lane >> 3);
    int c = colbase + lc;
    if (c >= 2560) {
      int sc = lane & 7;
      bf16x8 o;
#pragma unroll
      for (int rr = 0; rr < 8; ++rr) o[rr] = st[(sc * 8 + rr) * 56 + lc];
      __bf16* vp = Vt + (((size_t)b * 4 + ((c - 2560) >> 7)) * 128 + ((c - 2560) & 127)) * 2048
                   + s0 + wm * 64 + sc * 8;
      *(bf16x8*)vp = o;
    }
  }
}

// ---------------- RMSNorm + RoPE, in-place on bf16 Q/K ----------------
__global__ __launch_bounds__(256) void norm_rope(
    __bf16* __restrict__ Qb, __bf16* __restrict__ Kb,
    const float* __restrict__ qw, const float* __restrict__ kw,
    const float* __restrict__ cosT, const float* __restrict__ sinT) {
  const int tid = threadIdx.x, w = tid >> 6, lane = tid & 63;
  const int v = blockIdx.x * 4 + w;
  const bool isQ = v < 65536;
  __bf16* base = isQ ? Qb + (size_t)v * 128 : Kb + (size_t)(v - 65536) * 128;
  const int s = v & 2047;
  float x1 = (float)base[lane], x2 = (float)base[lane + 64];
  float ss = x1 * x1 + x2 * x2;
#pragma unroll
  for (int d = 32; d; d >>= 1) ss += __shfl_xor(ss, d);
  float rn = rsqrtf(ss * (1.0f / 128.0f) + 1e-8f);
  const float* wt = isQ ? qw : kw;
  float n1 = x1 * rn * (1.0f + wt[lane]);
  float n2 = x2 * rn * (1.0f + wt[lane + 64]);
  float c1 = cosT[s * 128 + lane], c2 = cosT[s * 128 + 64 + lane];
  float s1 = sinT[s * 128 + lane], s2 = sinT[s * 128 + 64 + lane];
  const float QSC = 0.08838834764831845f * 1.4426950408889634f;  // scale * log2(e)
  float post = isQ ? QSC : 1.0f;
  base[lane]      = (__bf16)((n1 * c1 - n2 * s1) * post);
  base[lane + 64] = (__bf16)((n2 * c2 + n1 * s2) * post);
}

// ---------------- output projection: 128x128 tile, BK=64, safe 2-phase dbuf -------
__device__ __forceinline__ void stage4(const __bf16* aS, const __bf16* bS,
                                       __bf16* Ab, __bf16* Bb, int wb8, size_t kt) {
#pragma unroll
  for (int l = 0; l < 2; ++l)
    gload_lds16(aS + (size_t)l * 131072 + kt, Ab + l * 4096 + wb8);
#pragma unroll
  for (int l = 0; l < 2; ++l)
    gload_lds16(bS + (size_t)l * 131072 + kt, Bb + l * 4096 + wb8);
}

__global__ __launch_bounds__(512, 4) void gemm_bt128(
    const __bf16* __restrict__ A, const __bf16* __restrict__ Bt,
    float* __restrict__ C) {
  extern __shared__ __bf16 smem[];
  const int K = 2048, N = 2048;
  const int tid = threadIdx.x;
  const int lane = tid & 63, w = tid >> 6;
  const int c15 = lane & 15, quad = lane >> 4;
  const int wm = w >> 2, wn = w & 3;
  const int id = blockIdx.x;
  const int swz = (id & 7) * 64 + (id >> 3);   // bijective: 512 = 8*64
  const int m0 = (swz >> 4) * 128, n0 = (swz & 15) * 128;

  const int srow = tid >> 3;
  const int scol = ((tid & 7) ^ (srow & 7)) * 8;
  const __bf16* aSrc = A + (size_t)(m0 + srow) * K + scol;
  const __bf16* bSrc = Bt + (size_t)(n0 + srow) * K + scol;
  const int wb8 = (tid & 448) * 8;

  f32x4 acc[4][2] = {};

  stage4(aSrc, bSrc, smem, smem + 8192, wb8, 0);
  __syncthreads();

  for (int t = 0; t < 32; ++t) {
    __bf16* Ab = smem + (t & 1) * 16384;
    __bf16* Bb = Ab + 8192;
    if (t < 31) {
      __bf16* An = smem + ((t + 1) & 1) * 16384;
      stage4(aSrc, bSrc, An, An + 8192, wb8, (size_t)(t + 1) * 64);
    }
    bf16x8 bF[2][2];
#pragma unroll
    for (int j = 0; j < 2; ++j) {
      int RB = wn * 32 + j * 16 + c15;
#pragma unroll
      for (int h = 0; h < 2; ++h)
        bF[j][h] = *(const bf16x8*)(Bb + RB * 64 + (((h * 4 + quad) ^ (RB & 7)) * 8));
    }
    __builtin_amdgcn_s_setprio(1);
#pragma unroll
    for (int i = 0; i < 4; ++i) {
      int RA = wm * 64 + i * 16 + c15;
      bf16x8 a0 = *(const bf16x8*)(Ab + RA * 64 + ((quad ^ (RA & 7)) * 8));
      bf16x8 a1 = *(const bf16x8*)(Ab + RA * 64 + (((4 + quad) ^ (RA & 7)) * 8));
#pragma unroll
      for (int j = 0; j < 2; ++j) {
        acc[i][j] = __builtin_amdgcn_mfma_f32_16x16x32_bf16(a0, bF[j][0], acc[i][j], 0, 0, 0);
        acc[i][j] = __builtin_amdgcn_mfma_f32_16x16x32_bf16(a1, bF[j][1], acc[i][j], 0, 0, 0);
      }
    }
    __builtin_amdgcn_s_setprio(0);
    __syncthreads();
  }

#pragma unroll
  for (int i = 0; i < 4; ++i) {
    int r0 = m0 + wm * 64 + i * 16 + quad * 4;
#pragma unroll
    for (int j = 0; j < 2; ++j) {
      int cc = n0 + wn * 32 + j * 16 + c15;
#pragma unroll
      for (int r = 0; r < 4; ++r)
        C[(size_t)(r0 + r) * N + cc] = acc[i][j][r];
    }
  }
}

// ---------------- Flash attention v8: R6 softmax + 3 blocks/CU -------------------
// R7's per-phase lgkmcnt(0)+sched_barrier fences serialized the loop (109us);
// reverted to R6's compute structure. Change vs R6: single K/V buffers (R5 A/B
// showed K-dbuf = 0 gain at this occupancy) shrink LDS 66K -> 50K = 3 blocks/CU
// (12 waves/CU, +50% TLP to hide the per-wave serial chain, which is the measured
// limiter: occupancy 13.6%, MfmaUtil 17.5%). R0-style staging: sync / stage K,V /
// sync / QK / softmax / PV. P write->read ordering is in-wave; compiler inserts
// lgkmcnt (no explicit fences - m141 lesson).
// Heavy+light pairing: b=0 heavy-first, b=1 light-first; CU pair (c, c+256) sums
// f(63-x)+f(x), balanced.
__global__ __launch_bounds__(256) void attn(
    const __bf16* __restrict__ Qb, const __bf16* __restrict__ Kb,
    const __bf16* __restrict__ Vt, const unsigned char* __restrict__ pad,
    const unsigned char* __restrict__ pad64, const int* __restrict__ winp,
    __bf16* __restrict__ O) {
  const int S = 2048;
  extern __shared__ __bf16 smem[];
  __bf16* Ks = smem;                    // [64 k][128 d]      8192 elems
  __bf16* Vs = smem + 8192;             // [128 d][64 s]      8192 elems
  __bf16* Ps = smem + 16384;            // [4 waves][32 q][72]
  const int tid = threadIdx.x, w = tid >> 6, lane = tid & 63;
  const int c15 = lane & 15, quad = lane >> 4;
  const int b = blockIdx.z;
  const int q0 = (b == 0) ? ((int)gridDim.x - 1 - (int)blockIdx.x) * 32
                          : (int)blockIdx.x * 32;
  const int kv = blockIdx.y;
  const int h = kv * 4 + w;
  const int W = *winp;
  const unsigned char* padb = pad + (size_t)b * S;
  const unsigned char* pad64b = pad64 + b * 32;
  const __bf16* Qh = Qb + (((size_t)b * 16 + h) * S) * 128;
  const __bf16* Kh = Kb + (((size_t)b * 4 + kv) * S) * 128;
  const __bf16* Vh = Vt + (((size_t)b * 4 + kv) * 128) * (size_t)S;
  __bf16* Pw = Ps + w * 2304;

  bf16x8 qf0[4], qf1[4];
#pragma unroll
  for (int c = 0; c < 4; ++c) {
    qf0[c] = *(const bf16x8*)(Qh + (size_t)(q0 + c15) * 128 + c * 32 + quad * 8);
    qf1[c] = *(const bf16x8*)(Qh + (size_t)(q0 + 16 + c15) * 128 + c * 32 + quad * 8);
  }

  f32x4 acc0[8] = {}, acc1[8] = {};
  float lsum0 = 0.f, lsum1 = 0.f;
  const int qi0 = q0 + c15, qi1 = q0 + 16 + c15;

  const int krow_i = lane >> 4, kch = lane & 15;
  const int vrow_i = lane >> 3, vch = lane & 7;

  int kb0 = q0 - W; if (kb0 < 0) kb0 = 0; kb0 &= ~63;
  const int kbend = q0 + 31;

  for (int kb = kb0; kb <= kbend; kb += 64) {
    __syncthreads();  // prev iteration's Ks/Vs reads complete
#pragma unroll
    for (int i = 0; i < 4; ++i) {
      int row = w * 16 + i * 4 + krow_i;
      gload_lds16(Kh + (size_t)(kb + row) * 128 + ((kch ^ (row & 15)) * 8),
                  Ks + (w * 16 + i * 4) * 128);
    }
#pragma unroll
    for (int i = 0; i < 4; ++i) {
      int row = w * 32 + i * 8 + vrow_i;
      gload_lds16(Vh + (size_t)row * S + kb + ((vch ^ (row & 7)) * 8),
                  Vs + (w * 32 + i * 8) * 64);
    }
    __syncthreads();  // staged K/V landed

    // swapped QK^T: sf[nb][r] = S[k = kb+nb*16+quad*4+r][q = q0(+16)+c15]
    f32x4 sf0[4], sf1[4];
#pragma unroll
    for (int nb = 0; nb < 4; ++nb) {
      f32x4 ca = {}, cb = {};
#pragma unroll
      for (int c = 0; c < 4; ++c) {
        bf16x8 kf = *(const bf16x8*)(Ks + (nb * 16 + c15) * 128 + (((c * 4 + quad) ^ c15) * 8));
        ca = __builtin_amdgcn_mfma_f32_16x16x32_bf16(kf, qf0[c], ca, 0, 0, 0);
        cb = __builtin_amdgcn_mfma_f32_16x16x32_bf16(kf, qf1[c], cb, 0, 0, 0);
      }
      sf0[nb] = ca; sf1[nb] = cb;
    }

    const bool fast = (kb + 63 <= q0) && (q0 + 31 - kb <= W) && (pad64b[kb >> 6] == 0);
    if (fast) {
#pragma unroll
      for (int nb = 0; nb < 4; ++nb) {
        float a0 = exp2f(sf0[nb][0]), a1 = exp2f(sf0[nb][1]);
        float a2 = exp2f(sf0[nb][2]), a3 = exp2f(sf0[nb][3]);
        lsum0 += (a0 + a1) + (a2 + a3);
        unsigned int w0, w1;
        asm("v_cvt_pk_bf16_f32 %0, %1, %2" : "=v"(w0) : "v"(a0), "v"(a1));
        asm("v_cvt_pk_bf16_f32 %0, %1, %2" : "=v"(w1) : "v"(a2), "v"(a3));
        unsigned long long pk0 = (unsigned long long)w0 | ((unsigned long long)w1 << 32);
        *(unsigned long long*)(Pw + (size_t)c15 * 72 + nb * 16 + quad * 4) = pk0;
        float b0 = exp2f(sf1[nb][0]), b1 = exp2f(sf1[nb][1]);
        float b2 = exp2f(sf1[nb][2]), b3 = exp2f(sf1[nb][3]);
        lsum1 += (b0 + b1) + (b2 + b3);
        unsigned int w2, w3;
        asm("v_cvt_pk_bf16_f32 %0, %1, %2" : "=v"(w2) : "v"(b0), "v"(b1));
        asm("v_cvt_pk_bf16_f32 %0, %1, %2" : "=v"(w3) : "v"(b2), "v"(b3));
        unsigned long long pk1 = (unsigned long long)w2 | ((unsigned long long)w3 << 32);
        *(unsigned long long*)(Pw + (size_t)(16 + c15) * 72 + nb * 16 + quad * 4) = pk1;
      }
    } else {
#pragma unroll
      for (int nb = 0; nb < 4; ++nb) {
        float p0[4], p1[4];
#pragma unroll
        for (int r = 0; r < 4; ++r) {
          int ki = kb + nb * 16 + quad * 4 + r;
          bool okp = (padb[ki] == 0);
          bool ok0 = (ki <= qi0) && ((qi0 - ki) <= W) && okp;
          bool ok1 = (ki <= qi1) && ((qi1 - ki) <= W) && okp;
          float e0 = exp2f(sf0[nb][r]);
          float e1 = exp2f(sf1[nb][r]);
          p0[r] = ok0 ? e0 : 0.0f;
          p1[r] = ok1 ? e1 : 0.0f;
        }
        lsum0 += (p0[0] + p0[1]) + (p0[2] + p0[3]);
        lsum1 += (p1[0] + p1[1]) + (p1[2] + p1[3]);
        unsigned int w0, w1, w2, w3;
        asm("v_cvt_pk_bf16_f32 %0, %1, %2" : "=v"(w0) : "v"(p0[0]), "v"(p0[1]));
        asm("v_cvt_pk_bf16_f32 %0, %1, %2" : "=v"(w1) : "v"(p0[2]), "v"(p0[3]));
        unsigned long long pk0 = (unsigned long long)w0 | ((unsigned long long)w1 << 32);
        *(unsigned long long*)(Pw + (size_t)c15 * 72 + nb * 16 + quad * 4) = pk0;
        asm("v_cvt_pk_bf16_f32 %0, %1, %2" : "=v"(w2) : "v"(p1[0]), "v"(p1[1]));
        asm("v_cvt_pk_bf16_f32 %0, %1, %2" : "=v"(w3) : "v"(p1[2]), "v"(p1[3]));
        unsigned long long pk1 = (unsigned long long)w2 | ((unsigned long long)w3 << 32);
        *(unsigned long long*)(Pw + (size_t)(16 + c15) * 72 + nb * 16 + quad * 4) = pk1;
      }
    }

    // PV: P is wave-private; compiler inserts the in-wave lgkmcnt for the
    // Pw write->read dependency (no explicit fence - R7 lesson).
    bf16x8 pf00 = *(const bf16x8*)(Pw + c15 * 72 + quad * 8);
    bf16x8 pf01 = *(const bf16x8*)(Pw + c15 * 72 + 32 + quad * 8);
    bf16x8 pf10 = *(const bf16x8*)(Pw + (16 + c15) * 72 + quad * 8);
    bf16x8 pf11 = *(const bf16x8*)(Pw + (16 + c15) * 72 + 32 + quad * 8);
#pragma unroll
    for (int nb = 0; nb < 8; ++nb) {
      int row = nb * 16 + c15;
      bf16x8 vf0 = *(const bf16x8*)(Vs + row * 64 + ((quad ^ (c15 & 7)) * 8));
      bf16x8 vf1 = *(const bf16x8*)(Vs + row * 64 + (((4 + quad) ^ (c15 & 7)) * 8));
      acc0[nb] = __builtin_amdgcn_mfma_f32_16x16x32_bf16(pf00, vf0, acc0[nb], 0, 0, 0);
      acc0[nb] = __builtin_amdgcn_mfma_f32_16x16x32_bf16(pf01, vf1, acc0[nb], 0, 0, 0);
      acc1[nb] = __builtin_amdgcn_mfma_f32_16x16x32_bf16(pf10, vf0, acc1[nb], 0, 0, 0);
      acc1[nb] = __builtin_amdgcn_mfma_f32_16x16x32_bf16(pf11, vf1, acc1[nb], 0, 0, 0);
    }
  }

  // lsum lives at q=c15 (quads hold k-partials); reduce across quads, then
  // redistribute inv to writer lanes.
  lsum0 += __shfl_xor(lsum0, 16);
  lsum0 += __shfl_xor(lsum0, 32);
  lsum1 += __shfl_xor(lsum1, 16);
  lsum1 += __shfl_xor(lsum1, 32);
  float inv0 = 1.0f / lsum0, inv1 = 1.0f / lsum1;
  float iv0[4], iv1[4];
#pragma unroll
  for (int r = 0; r < 4; ++r) {
    iv0[r] = __shfl(inv0, quad * 4 + r);
    iv1[r] = __shfl(inv1, quad * 4 + r);
  }
#pragma unroll
  for (int nb = 0; nb < 8; ++nb)
#pragma unroll
    for (int r = 0; r < 4; ++r) {
      size_t idx = ((size_t)b * S + q0 + quad * 4 + r) * 2048 + h * 128 + nb * 16 + c15;
      O[idx] = (__bf16)(acc0[nb][r] * iv0[r]);
      O[idx + (size_t)16 * 2048] = (__bf16)(acc1[nb][r] * iv1[r]);
    }
}

// ---------------- launch ----------------
extern "C" void kernel_launch(void* const* d_in, const int* in_sizes, int n_in,
                              void* d_out, int out_size, void* d_ws, size_t ws_size,
                              hipStream_t stream) {
  const float* x    = (const float*)d_in[0];
  const float* Wq   = (const float*)d_in[1];
  const float* Wk   = (const float*)d_in[2];
  const float* Wv   = (const float*)d_in[3];
  const float* Wo   = (const float*)d_in[4];
  const float* qw   = (const float*)d_in[5];
  const float* kw   = (const float*)d_in[6];
  const float* cosT = (const float*)d_in[7];
  const float* sinT = (const float*)d_in[8];
  const unsigned char* pad = (const unsigned char*)d_in[9];
  const int* win    = (const int*)d_in[10];

  char* ws = (char*)d_ws;
  __bf16* xb    = (__bf16*)(ws + 0);          // 4096x2048 bf16        (16 MB)
  __bf16* Wqkvt = (__bf16*)(ws + 16777216);   // 3072x2048 bf16        (12 MB)
  __bf16* Wot   = (__bf16*)(ws + 29360128);   // 2048x2048 bf16        (8 MB)
  __bf16* Qb    = (__bf16*)(ws + 37748736);   // [2][16][2048][128]    (16 MB)
  __bf16* Kb    = (__bf16*)(ws + 54525952);   // [2][4][2048][128]     (4 MB)
  __bf16* Vt    = (__bf16*)(ws + 58720256);   // [2][4][128][2048]     (4 MB)
  __bf16* Ob    = (__bf16*)(ws + 62914560);   // 4096x2048 bf16        (16 MB)
  unsigned char* pad64 = (unsigned char*)(ws + 79691776);  // [2][32]

  static int qkv_attr = (int)hipFuncSetAttribute(
      (const void*)gemm_qkv192, hipFuncAttributeMaxDynamicSharedMemorySize, 81920);
  (void)qkv_attr;
  static int bt_attr = (int)hipFuncSetAttribute(
      (const void*)gemm_bt128, hipFuncAttributeMaxDynamicSharedMemorySize, 65536);
  (void)bt_attr;
  static int at_attr = (int)hipFuncSetAttribute(
      (const void*)attn, hipFuncAttributeMaxDynamicSharedMemorySize, 51200);
  (void)at_attr;

  prep<<<dim3(288, 64, 1), dim3(32, 8, 1), 0, stream>>>(
      Wq, Wk, Wv, Wo, (const float4*)x, (const unsigned long long*)pad,
      Wqkvt, Wot, (bf16x4*)xb, pad64);

  gemm_qkv192<<<dim3(512, 1, 1), 512, 81920, stream>>>(xb, Wqkvt, Qb, Kb, Vt);

  norm_rope<<<20480, 256, 0, stream>>>(Qb, Kb, qw, kw, cosT, sinT);

  attn<<<dim3(64, 4, 2), 256, 51200, stream>>>(Qb, Kb, Vt, pad, pad64, win, Ob);

  gemm_bt128<<<dim3(512, 1, 1), 512, 65536, stream>>>(Ob, Wot, (float*)d_out);
}